// Round 8
// baseline (257.785 us; speedup 1.0000x reference)
//
#include <hip/hip_runtime.h>
#include <hip/hip_bf16.h>

// RNN wavefunction log-prob: N=128 steps, B=8192, H=128, D=2 (one-hot).
// R15: R14 (fused 2-tile block, free ILP) + residency fix. R14 ran at
// 1 block/CU (unified regs >128 under launch_bounds(512,2)). Here:
// launch_bounds(512,4) forces unified <=128, and the step processes
// tile A then tile B in SEQUENTIAL scoped phases so the two fragment
// arrays (32 VGPRs each) never coexist: peak ~= 48 wt + 32 frag + 16
// acc + misc ~= 111 <= 128. Target: 2 blocks/CU = 4 tile-chains/CU
// (first config to beat the 2-chain register cap). One barrier/step.
// Tripwires: WRITE_SIZE in MBs = loop spill -> revert; Occupancy ~25%
// = still 1 block -> unified still >128.

#define NSTEP 128
#define BTOT  8192
#define HID   128
#define SPB   32            // samples per block (two 16-wide tiles)
#define NBLK  (BTOT / SPB)  // 256
#define NTHR  512

typedef __attribute__((ext_vector_type(8))) short bf16x8;
typedef __attribute__((ext_vector_type(4))) float f32x4;
typedef __attribute__((ext_vector_type(2))) float f32x2;
typedef __attribute__((ext_vector_type(2))) unsigned uint32x2;

__device__ __forceinline__ short f2bf(float v) {
    unsigned u = __builtin_bit_cast(unsigned, v);
    u += 0x7FFFu + ((u >> 16) & 1u);
    return (short)(u >> 16);
}
// two f32 -> packed bf16x2 via v_cvt_pk_bf16_f32
__device__ __forceinline__ unsigned cvt2bf(float a, float b) {
    __hip_bfloat162 h2 = __float22bfloat162_rn(make_float2(a, b));
    unsigned u; __builtin_memcpy(&u, &h2, sizeof(u));
    return u;
}
// tanh on a pair: 2 exp + ONE rcp (shared via rcp(d0*d1))
__device__ __forceinline__ f32x2 tanh2(f32x2 x) {
    f32x2 z = x * 2.885390081777927f;            // 2x*log2(e)
    float e0 = __builtin_exp2f(z.x);
    float e1 = __builtin_exp2f(z.y);
    f32x2 d = {e0 + 1.0f, e1 + 1.0f};
    float r = __builtin_amdgcn_rcpf(d.x * d.y);
    f32x2 inv = {r * d.y, r * d.x};              // 1/d.x, 1/d.y
    return inv * -2.0f + 1.0f;
}

__global__ __launch_bounds__(NTHR, 4) void rnn_wf_kernel(
    const float* __restrict__ samples,  // (128, 8192, 2)
    const float* __restrict__ Wih0,     // (128, 2)
    const float* __restrict__ bih0,     // (128,)
    const float* __restrict__ Whh0,     // (128, 128)
    const float* __restrict__ bhh0,     // (128,)
    const float* __restrict__ Wih1,     // (128, 128)
    const float* __restrict__ bih1,     // (128,)
    const float* __restrict__ Whh1,     // (128, 128)
    const float* __restrict__ bhh1,     // (128,)
    const float* __restrict__ Wd,       // (2, 128)
    const float* __restrict__ bd,       // (2,)
    float* __restrict__ out)            // (1, 8192)
{
    __shared__ short sH0A[2][16 * HID];
    __shared__ short sH1A[2][16 * HID];
    __shared__ short sH0B[2][16 * HID];
    __shared__ short sH1B[2][16 * HID];
    __shared__ unsigned sMask[NSTEP];            // bits 0-15 tile A, 16-31 tile B
    __shared__ float sLd[2][NSTEP * 17];         // logit diffs per tile
    __shared__ __attribute__((aligned(16))) float sBias[4 * HID];
    // segments: [0:128)=WA (b0+Wih0 col0), [128:256)=WB (col1),
    //           [256:384)=B1, [384:512)=B0 plain
    __shared__ __attribute__((aligned(16))) short sFwd[4 * 64 * 8];

    const int tid  = threadIdx.x;
    const int b0   = blockIdx.x * SPB;
    const int w    = tid >> 6;          // wave 0..7, owns n in [16w, 16w+16)
    const int lane = tid & 63;
    const int q    = lane >> 4;
    const int c    = lane & 15;

    // ---- decode f32 one-hot samples -> per-step 32-bit masks ----
    if (tid < NSTEP) {
        unsigned msk = 0;
        #pragma unroll
        for (int m = 0; m < SPB; ++m) {
            float e1 = samples[((size_t)tid * BTOT + b0 + m) * 2 + 1];
            if (e1 > 0.5f) msk |= (1u << m);
        }
        sMask[tid] = msk;
    }
    // ---- biases into LDS ----
    if (tid >= NSTEP && tid < NSTEP + HID) {
        const int n = tid - NSTEP;
        const float bb = bih0[n] + bhh0[n];
        sBias[n]       = bb + Wih0[n * 2 + 0];
        sBias[128 + n] = bb + Wih0[n * 2 + 1];
        sBias[256 + n] = bih1[n] + bhh1[n];
        sBias[384 + n] = bb;
    }
    // ---- dense-head fragments into LDS ----
    if (tid >= 256 && tid < 512) {
        const int t2 = tid - 256;
        const int kb = t2 >> 6, l = t2 & 63, cc = l & 15, qq = l >> 4;
        bf16x8 v;
        #pragma unroll
        for (int j = 0; j < 8; ++j)
            v[j] = (cc < 2) ? f2bf(Wd[cc * HID + kb * 32 + qq * 8 + j]) : (short)0;
        *reinterpret_cast<bf16x8*>(&sFwd[(kb * 64 + l) * 8]) = v;
    }

    // ---- weight A-fragments: lane holds W[16w+c][kb*32+q*8 .. +8] ----
    bf16x8 fhh0[4], fih1[4], fhh1[4];
    {
        const int nn = w * 16 + c;
        #pragma unroll
        for (int kb = 0; kb < 4; ++kb) {
            const int off = nn * HID + kb * 32 + q * 8;
            bf16x8 v0, v1, v2;
            #pragma unroll
            for (int j = 0; j < 8; ++j) {
                v0[j] = f2bf(Whh0[off + j]);
                v1[j] = f2bf(Wih1[off + j]);
                v2[j] = f2bf(Whh1[off + j]);
            }
            fhh0[kb] = v0; fih1[kb] = v1; fhh1[kb] = v2;
        }
    }
    const float bd0 = bd[0], bd1 = bd[1];

    // ---- t-invariant LDS indices ----
    int ra[4];
    #pragma unroll
    for (int kb = 0; kb < 4; ++kb)
        ra[kb] = c * HID + (((kb * 4 + q) ^ c) << 3);
    // write: h'[m=c][n = 16w + 4q + r]; 8-block = 2w + (q>>1), half q&1
    const int wa = c * HID + (((2 * w + (q >> 1)) ^ c) << 3) + ((q & 1) << 2);
    const int ib = w * 16 + q * 4;   // float index into bias arrays

    bool bmPrevA = false, bmPrevB = false;

    // write one layer's 4 tanh'd values (b64)
    auto storeL = [&](short* buf, const f32x4& a) {
        f32x2 t0 = tanh2((f32x2){a[0], a[1]});
        f32x2 t1 = tanh2((f32x2){a[2], a[3]});
        uint32x2 v = {cvt2bf(t0.x, t0.y), cvt2bf(t1.x, t1.y)};
        *reinterpret_cast<uint32x2*>(&buf[wa]) = v;
    };

    __syncthreads();                 // sMask, sBias, sFwd published

    // ---- i = 0: h0(0) = tanh(b0), both tiles ----
    {
        f32x4 bv = *reinterpret_cast<const f32x4*>(&sBias[384 + ib]);
        storeL(sH0A[1], bv);
        storeL(sH0B[1], bv);
    }
    __syncthreads();

    // ---- i = 1: h0(1), h1(0), both tiles (sequential phases) ----
    {
        const unsigned msk = sMask[0];
        {   // tile A
            const bool bmA = (msk >> c) & 1u;
            const float* bpA = bmA ? (sBias + 128) : sBias;
            f32x4 a0A = *reinterpret_cast<const f32x4*>(&bpA[ib]);
            f32x4 a1A = *reinterpret_cast<const f32x4*>(&sBias[256 + ib]);
            #pragma unroll
            for (int kb = 0; kb < 4; ++kb) {
                bf16x8 f0A = *reinterpret_cast<const bf16x8*>(&sH0A[1][ra[kb]]);
                a0A = __builtin_amdgcn_mfma_f32_16x16x32_bf16(fhh0[kb], f0A, a0A, 0, 0, 0);
                a1A = __builtin_amdgcn_mfma_f32_16x16x32_bf16(fih1[kb], f0A, a1A, 0, 0, 0);
            }
            storeL(sH0A[0], a0A);
            storeL(sH1A[0], a1A);
            bmPrevA = bmA;
        }
        {   // tile B
            const bool bmB = (msk >> (16 + c)) & 1u;
            const float* bpB = bmB ? (sBias + 128) : sBias;
            f32x4 a0B = *reinterpret_cast<const f32x4*>(&bpB[ib]);
            f32x4 a1B = *reinterpret_cast<const f32x4*>(&sBias[256 + ib]);
            #pragma unroll
            for (int kb = 0; kb < 4; ++kb) {
                bf16x8 f0B = *reinterpret_cast<const bf16x8*>(&sH0B[1][ra[kb]]);
                a0B = __builtin_amdgcn_mfma_f32_16x16x32_bf16(fhh0[kb], f0B, a0B, 0, 0, 0);
                a1B = __builtin_amdgcn_mfma_f32_16x16x32_bf16(fih1[kb], f0B, a1B, 0, 0, 0);
            }
            storeL(sH0B[0], a0B);
            storeL(sH1B[0], a1B);
            bmPrevB = bmB;
        }
        __syncthreads();
    }

    // ---- main: i = 2..127, one barrier per iteration, sequential phases ----
    auto stepMain = [&](int i,
                        const short* r0A, const short* r1A, short* w0A, short* w1A,
                        const short* r0B, const short* r1B, short* w0B, short* w1B) {
        const unsigned msk = sMask[i - 1];
        {   // ---- tile A phase ----
            const bool bmA = (msk >> c) & 1u;
            const float* bpA = bmA ? (sBias + 128) : sBias;
            f32x4 a0A = *reinterpret_cast<const f32x4*>(&bpA[ib]);
            f32x4 a1A = *reinterpret_cast<const f32x4*>(&sBias[256 + ib]);
            bf16x8 f0A[4], f1A[4];
            #pragma unroll
            for (int kb = 0; kb < 4; ++kb) {
                f0A[kb] = *reinterpret_cast<const bf16x8*>(&r0A[ra[kb]]);
                f1A[kb] = *reinterpret_cast<const bf16x8*>(&r1A[ra[kb]]);
            }
            #pragma unroll
            for (int kb = 0; kb < 4; ++kb) {
                a0A = __builtin_amdgcn_mfma_f32_16x16x32_bf16(fhh0[kb], f0A[kb], a0A, 0, 0, 0);
                a1A = __builtin_amdgcn_mfma_f32_16x16x32_bf16(fhh1[kb], f1A[kb], a1A, 0, 0, 0);
            }
            #pragma unroll
            for (int kb = 0; kb < 4; ++kb)
                a1A = __builtin_amdgcn_mfma_f32_16x16x32_bf16(fih1[kb], f0A[kb], a1A, 0, 0, 0);
            if (w == (i & 7)) {
                f32x4 aL = {bd0, bd1, 0.f, 0.f};
                #pragma unroll
                for (int kb = 0; kb < 4; ++kb) {
                    bf16x8 fw = *reinterpret_cast<const bf16x8*>(&sFwd[(kb * 64 + lane) * 8]);
                    aL = __builtin_amdgcn_mfma_f32_16x16x32_bf16(fw, f1A[kb], aL, 0, 0, 0);
                }
                if (q == 0)
                    sLd[0][(i - 2) * 17 + c] = bmPrevA ? (aL[0] - aL[1]) : (aL[1] - aL[0]);
            }
            bmPrevA = bmA;
            storeL(w0A, a0A);            // h0(i)
            storeL(w1A, a1A);            // h1(i-1)
        }
        {   // ---- tile B phase ----
            const bool bmB = (msk >> (16 + c)) & 1u;
            const float* bpB = bmB ? (sBias + 128) : sBias;
            f32x4 a0B = *reinterpret_cast<const f32x4*>(&bpB[ib]);
            f32x4 a1B = *reinterpret_cast<const f32x4*>(&sBias[256 + ib]);
            bf16x8 f0B[4], f1B[4];
            #pragma unroll
            for (int kb = 0; kb < 4; ++kb) {
                f0B[kb] = *reinterpret_cast<const bf16x8*>(&r0B[ra[kb]]);
                f1B[kb] = *reinterpret_cast<const bf16x8*>(&r1B[ra[kb]]);
            }
            #pragma unroll
            for (int kb = 0; kb < 4; ++kb) {
                a0B = __builtin_amdgcn_mfma_f32_16x16x32_bf16(fhh0[kb], f0B[kb], a0B, 0, 0, 0);
                a1B = __builtin_amdgcn_mfma_f32_16x16x32_bf16(fhh1[kb], f1B[kb], a1B, 0, 0, 0);
            }
            #pragma unroll
            for (int kb = 0; kb < 4; ++kb)
                a1B = __builtin_amdgcn_mfma_f32_16x16x32_bf16(fih1[kb], f0B[kb], a1B, 0, 0, 0);
            if (w == ((i + 4) & 7)) {
                f32x4 aL = {bd0, bd1, 0.f, 0.f};
                #pragma unroll
                for (int kb = 0; kb < 4; ++kb) {
                    bf16x8 fw = *reinterpret_cast<const bf16x8*>(&sFwd[(kb * 64 + lane) * 8]);
                    aL = __builtin_amdgcn_mfma_f32_16x16x32_bf16(fw, f1B[kb], aL, 0, 0, 0);
                }
                if (q == 0)
                    sLd[1][(i - 2) * 17 + c] = bmPrevB ? (aL[0] - aL[1]) : (aL[1] - aL[0]);
            }
            bmPrevB = bmB;
            storeL(w0B, a0B);
            storeL(w1B, a1B);
        }
        __syncthreads();
    };

    for (int i = 2; i < NSTEP; i += 2) {
        stepMain(i,
                 sH0A[0], sH1A[0], sH0A[1], sH1A[1],
                 sH0B[0], sH1B[0], sH0B[1], sH1B[1]);
        stepMain(i + 1,
                 sH0A[1], sH1A[1], sH0A[0], sH1A[0],
                 sH0B[1], sH1B[1], sH0B[0], sH1B[0]);
    }

    // ---- i = 128: h1(127), logits(126), sequential phases ----
    {
        {   // tile A
            f32x4 a1A = *reinterpret_cast<const f32x4*>(&sBias[256 + ib]);
            bf16x8 f0A[4], f1A[4];
            #pragma unroll
            for (int kb = 0; kb < 4; ++kb) {
                f0A[kb] = *reinterpret_cast<const bf16x8*>(&sH0A[0][ra[kb]]);  // h0(127)
                f1A[kb] = *reinterpret_cast<const bf16x8*>(&sH1A[0][ra[kb]]);  // h1(126)
            }
            #pragma unroll
            for (int kb = 0; kb < 4; ++kb)
                a1A = __builtin_amdgcn_mfma_f32_16x16x32_bf16(fhh1[kb], f1A[kb], a1A, 0, 0, 0);
            #pragma unroll
            for (int kb = 0; kb < 4; ++kb)
                a1A = __builtin_amdgcn_mfma_f32_16x16x32_bf16(fih1[kb], f0A[kb], a1A, 0, 0, 0);
            if (w == 0) {                // 128 & 7 == 0
                f32x4 aL = {bd0, bd1, 0.f, 0.f};
                #pragma unroll
                for (int kb = 0; kb < 4; ++kb) {
                    bf16x8 fw = *reinterpret_cast<const bf16x8*>(&sFwd[(kb * 64 + lane) * 8]);
                    aL = __builtin_amdgcn_mfma_f32_16x16x32_bf16(fw, f1A[kb], aL, 0, 0, 0);
                }
                if (q == 0)
                    sLd[0][126 * 17 + c] = bmPrevA ? (aL[0] - aL[1]) : (aL[1] - aL[0]);
            }
            storeL(sH1A[1], a1A);        // h1(127)
        }
        {   // tile B
            f32x4 a1B = *reinterpret_cast<const f32x4*>(&sBias[256 + ib]);
            bf16x8 f0B[4], f1B[4];
            #pragma unroll
            for (int kb = 0; kb < 4; ++kb) {
                f0B[kb] = *reinterpret_cast<const bf16x8*>(&sH0B[0][ra[kb]]);
                f1B[kb] = *reinterpret_cast<const bf16x8*>(&sH1B[0][ra[kb]]);
            }
            #pragma unroll
            for (int kb = 0; kb < 4; ++kb)
                a1B = __builtin_amdgcn_mfma_f32_16x16x32_bf16(fhh1[kb], f1B[kb], a1B, 0, 0, 0);
            #pragma unroll
            for (int kb = 0; kb < 4; ++kb)
                a1B = __builtin_amdgcn_mfma_f32_16x16x32_bf16(fih1[kb], f0B[kb], a1B, 0, 0, 0);
            if (w == 4) {                // (128+4) & 7 == 4
                f32x4 aL = {bd0, bd1, 0.f, 0.f};
                #pragma unroll
                for (int kb = 0; kb < 4; ++kb) {
                    bf16x8 fw = *reinterpret_cast<const bf16x8*>(&sFwd[(kb * 64 + lane) * 8]);
                    aL = __builtin_amdgcn_mfma_f32_16x16x32_bf16(fw, f1B[kb], aL, 0, 0, 0);
                }
                if (q == 0)
                    sLd[1][126 * 17 + c] = bmPrevB ? (aL[0] - aL[1]) : (aL[1] - aL[0]);
            }
            storeL(sH1B[1], a1B);
        }
        __syncthreads();
    }
    // ---- i = 129: logits(127), waves 1 (A) and 5 (B) ----
    if (w == 1) {
        f32x4 aL = {bd0, bd1, 0.f, 0.f};
        #pragma unroll
        for (int kb = 0; kb < 4; ++kb) {
            bf16x8 f1 = *reinterpret_cast<const bf16x8*>(&sH1A[1][ra[kb]]);
            bf16x8 fw = *reinterpret_cast<const bf16x8*>(&sFwd[(kb * 64 + lane) * 8]);
            aL = __builtin_amdgcn_mfma_f32_16x16x32_bf16(fw, f1, aL, 0, 0, 0);
        }
        if (q == 0) {
            const bool bit = (sMask[NSTEP - 1] >> c) & 1u;
            sLd[0][127 * 17 + c] = bit ? (aL[0] - aL[1]) : (aL[1] - aL[0]);
        }
    }
    if (w == 5) {
        f32x4 aL = {bd0, bd1, 0.f, 0.f};
        #pragma unroll
        for (int kb = 0; kb < 4; ++kb) {
            bf16x8 f1 = *reinterpret_cast<const bf16x8*>(&sH1B[1][ra[kb]]);
            bf16x8 fw = *reinterpret_cast<const bf16x8*>(&sFwd[(kb * 64 + lane) * 8]);
            aL = __builtin_amdgcn_mfma_f32_16x16x32_bf16(fw, f1, aL, 0, 0, 0);
        }
        if (q == 0) {
            const bool bit = (sMask[NSTEP - 1] >> (16 + c)) & 1u;
            sLd[1][127 * 17 + c] = bit ? (aL[0] - aL[1]) : (aL[1] - aL[0]);
        }
    }
    __syncthreads();

    // ---- final pass: lp(s) = sum_t -log(1 + exp(diff_t)) ----
    {
        const int s  = tid >> 4;      // sample 0..31
        const int k  = tid & 15;      // step sub-index
        const int tb = s >> 4;        // tile 0/1
        const int si = s & 15;        // sample within tile
        float acc = 0.0f;
        #pragma unroll
        for (int j = 0; j < 8; ++j) {
            const float x = sLd[tb][(j * 16 + k) * 17 + si];
            const float ed = __builtin_exp2f(x * 1.4426950408889634f);
            acc -= 0.6931471805599453f * __builtin_log2f(1.0f + ed);
        }
        #pragma unroll
        for (int off = 1; off < 16; off <<= 1)
            acc += __shfl_xor(acc, off, 64);
        if (k == 0)
            out[b0 + s] = acc;
    }
}

extern "C" void kernel_launch(void* const* d_in, const int* in_sizes, int n_in,
                              void* d_out, int out_size, void* d_ws, size_t ws_size,
                              hipStream_t stream) {
    rnn_wf_kernel<<<NBLK, NTHR, 0, stream>>>(
        (const float*)d_in[0],  // samples
        (const float*)d_in[1],  // W_ih0
        (const float*)d_in[2],  // b_ih0
        (const float*)d_in[3],  // W_hh0
        (const float*)d_in[4],  // b_hh0
        (const float*)d_in[5],  // W_ih1
        (const float*)d_in[6],  // b_ih1
        (const float*)d_in[7],  // W_hh1
        (const float*)d_in[8],  // b_hh1
        (const float*)d_in[9],  // W_dense
        (const float*)d_in[10], // b_dense
        (float*)d_out);
}